// Round 1
// baseline (104.693 us; speedup 1.0000x reference)
//
#include <hip/hip_runtime.h>
#include <cstdint>

#define NQ 16
#define NL 4
#define NX 65536     // 2^16 basis states
#define NBATCH 64
#define NOUT 784

// ---------------------------------------------------------------------------
// Compile-time circuit algebra.
// Circuit: U = ring3·RX3·ring2·RX2·ring1·RX1·ring0·RX0·(init RX from z)
// Push all rings to the end: U = C_total · Π_k exp(-i θ_k/2 X^{v_k}) · initRX.
// Layer-l RX on qubit q: v = e_q conjugated by rings l-1 .. 0 (innermost ring
// l-1 first; within a ring, CNOT(15,0) first then 14,...,0).
//   X-rule under CNOT(c,t): if bit c set in v, toggle bit t.
// Measurement: C_total† Z_q C_total = Z^{m_q}: conjugate e_q by ring3 first
// down to ring0, within ring CNOT(15,0) first. Z-rule: if bit t set, toggle c.
// Then (X basis, phase state):
//   <Z_q>_s = 2^-16 Σ_x cos( Σ_{k: pc(v_k&m_q) odd} θ_k (-1)^{pc(v_k&x)} )
// where the θ_k are {z_{s,j} (masks e_j)} ∪ {W_{l,k} (masks v_{l,k})}.
// ---------------------------------------------------------------------------
struct Tables {
  uint16_t m[NQ];
  int32_t  cnt[NQ];
  uint16_t kmask[NQ][NL*NQ];
  uint8_t  kidx[NQ][NL*NQ];
};

constexpr Tables make_tables() {
  Tables T{};
  uint16_t v[NL*NQ] = {};
  for (int l = 0; l < NL; l++)
    for (int q = 0; q < NQ; q++) {
      unsigned vv = 1u << q;
      for (int L = l - 1; L >= 0; --L)
        for (int k = NQ - 1; k >= 0; --k) {
          unsigned t = (unsigned)((k + 1) & (NQ - 1));
          if ((vv >> k) & 1u) vv ^= (1u << t);
        }
      v[l*NQ + q] = (uint16_t)vv;
    }
  for (int q = 0; q < NQ; q++) {
    unsigned mm = 1u << q;
    for (int L = NL - 1; L >= 0; --L)
      for (int k = NQ - 1; k >= 0; --k) {
        unsigned t = (unsigned)((k + 1) & (NQ - 1));
        if ((mm >> t) & 1u) mm ^= (1u << k);
      }
    T.m[q] = (uint16_t)mm;
  }
  for (int q = 0; q < NQ; q++) {
    int c = 0;
    for (int i = 0; i < NL*NQ; i++) {
      unsigned inter = (unsigned)(v[i] & T.m[q]);
      int pc = 0;
      for (int b = 0; b < 16; b++) pc += (int)((inter >> b) & 1u);
      if (pc & 1) { T.kmask[q][c] = v[i]; T.kidx[q][c] = (uint8_t)i; c++; }
    }
    T.cnt[q] = c;
  }
  return T;
}

constexpr Tables H_TAB = make_tables();
__constant__ Tables TAB = H_TAB;

// kA: dW[q][x] = Σ_{included layer rotations} W[l*16+k] * (-1)^{pc(v & x)}
__global__ __launch_bounds__(256) void kA(const float* __restrict__ W,
                                          float* __restrict__ dW) {
  __shared__ float sW[NL*NQ];
  int t = threadIdx.x;
  if (t < NL*NQ) sW[t] = W[t];
  __syncthreads();
  int b = blockIdx.x;            // 4096 blocks
  int q = b >> 8;                // 16 q values
  unsigned x = (((unsigned)b & 255u) << 8) | (unsigned)t;
  int n = TAB.cnt[q];
  float acc = 0.f;
  for (int i = 0; i < n; i++) {
    unsigned msk = TAB.kmask[q][i];
    float w = sW[TAB.kidx[q][i]];
    unsigned sgn = (unsigned)(__popc(msk & x) & 1) << 31;
    acc += __uint_as_float(__float_as_uint(w) ^ sgn);
  }
  dW[((unsigned)q << 16) | x] = acc;
}

// kB: one block per (sample, q). Uses Δ(x^m) = -Δ(x) to sum half-space only.
__global__ __launch_bounds__(256) void kB(const float* __restrict__ z,
                                          const float* __restrict__ dW,
                                          float* __restrict__ zq) {
  __shared__ float zlo[256], zhi[256];
  __shared__ float part[4];
  int b = blockIdx.x;            // 1024 = 64 samples * 16 q
  int s = b >> 4, q = b & 15;
  unsigned m = TAB.m[q];
  int t = threadIdx.x;
  if (m == 0u) {                 // uniform branch: <Z>=1 (no odd-overlap terms)
    if (t == 0) zq[s*NQ + q] = 1.0f;
    return;
  }
  // z-part lookup tables over the two bytes of x (only bits in m contribute)
  float lo = 0.f, hi = 0.f;
  const float* zs = z + s*NQ;
  #pragma unroll
  for (int j = 0; j < 8; j++) {
    if ((m >> j) & 1u)       lo += ((t >> j) & 1) ? -zs[j]   : zs[j];
    if ((m >> (j+8)) & 1u)   hi += ((t >> j) & 1) ? -zs[j+8] : zs[j+8];
  }
  zlo[t] = lo; zhi[t] = hi;
  __syncthreads();

  unsigned b0 = (unsigned)__ffs(m) - 1u;     // lowest set bit of m
  unsigned lowmask = (1u << b0) - 1u;
  const float* dq = dW + ((unsigned)q << 16);
  float acc = 0.f;
  for (int y = t; y < NX/2; y += 256) {
    unsigned uy = (unsigned)y;
    unsigned x = (((uy & ~lowmask) << 1) | (uy & lowmask));  // bit b0 == 0 half
    float d = zlo[x & 255u] + zhi[(x >> 8) & 255u] + dq[x];
    acc += __cosf(d);
  }
  // wave (64-lane) + block reduction
  for (int off = 32; off > 0; off >>= 1) acc += __shfl_down(acc, off, 64);
  if ((t & 63) == 0) part[t >> 6] = acc;
  __syncthreads();
  if (t == 0) {
    float r = (part[0] + part[1] + part[2] + part[3]) * (1.0f / 32768.0f);
    zq[s*NQ + q] = r;
  }
}

// kC: out[s, o] = tanh( Σ_j zq[s][j] * w_lin[o][j] + b_lin[o] )
__global__ __launch_bounds__(256) void kC(const float* __restrict__ zq,
                                          const float* __restrict__ wl,
                                          const float* __restrict__ bl,
                                          float* __restrict__ out) {
  int b = blockIdx.x;            // 256 = 64 samples * 4 chunks
  int s = b >> 2;
  int o = ((b & 3) << 8) | threadIdx.x;
  if (o >= NOUT) return;
  float acc = bl[o];
  const float* zr = zq + s*NQ;
  const float* wr = wl + o*NQ;
  #pragma unroll
  for (int j = 0; j < NQ; j++) acc += zr[j] * wr[j];
  out[s*NOUT + o] = tanhf(acc);
}

extern "C" void kernel_launch(void* const* d_in, const int* in_sizes, int n_in,
                              void* d_out, int out_size, void* d_ws, size_t ws_size,
                              hipStream_t stream) {
  const float* z  = (const float*)d_in[0];  // (64,16)
  const float* W  = (const float*)d_in[1];  // (4,16)
  const float* wl = (const float*)d_in[2];  // (784,16)
  const float* bl = (const float*)d_in[3];  // (784,)
  float* out = (float*)d_out;               // (64,1,28,28) f32

  float* dW = (float*)d_ws;                 // 16*65536 f32 = 4 MB
  float* zq = dW + NQ*NX;                   // 64*16 f32

  kA<<<4096, 256, 0, stream>>>(W, dW);
  kB<<<1024, 256, 0, stream>>>(z, dW, zq);
  kC<<<256, 256, 0, stream>>>(zq, wl, bl, out);
}